// Round 1
// baseline (564.927 us; speedup 1.0000x reference)
//
#include <hip/hip_runtime.h>

// DEC soft assignment: q = rownorm(1/(1 + ||x-c||^2)), ALPHA=1 so power term is identity.
// Strategy: bf16 MFMA GEMM for x.c^T (error budget analysis: dq ~ 2e-7 << 4e-5 threshold),
// fp32 x^2/c^2, full 512-cluster rows per block so normalization fuses (no 2nd 512MB pass).

typedef __attribute__((ext_vector_type(8))) short short8_t;
typedef __attribute__((ext_vector_type(4))) short short4_t;
typedef __attribute__((ext_vector_type(4))) float f32x4;

#define NROWS 131072
#define DDIM  512
#define NCL   512
#define BK    32
#define MT    32
#define APAD  40   // A row stride in shorts (pad 32->40 for 2-way-free ds_read_b128)

__device__ __forceinline__ unsigned short f2bf(float f) {
    // round-to-nearest-even fp32 -> bf16
    unsigned u = __float_as_uint(f);
    u += 0x7FFFu + ((u >> 16) & 1u);
    return (unsigned short)(u >> 16);
}

// ---- prep: convert centers to bf16, compute ||c_k||^2 in fp32 ----
__global__ __launch_bounds__(128) void prep_centers(
        const float* __restrict__ c, unsigned short* __restrict__ cb,
        float* __restrict__ c2) {
    const int k = blockIdx.x, t = threadIdx.x;
    float4 v = ((const float4*)(c + k * DDIM))[t];
    float ss = v.x * v.x + v.y * v.y + v.z * v.z + v.w * v.w;
    short4_t s;
    s.x = (short)f2bf(v.x); s.y = (short)f2bf(v.y);
    s.z = (short)f2bf(v.z); s.w = (short)f2bf(v.w);
    ((short4_t*)(cb + k * DDIM))[t] = s;
#pragma unroll
    for (int off = 32; off >= 1; off >>= 1) ss += __shfl_xor(ss, off, 64);
    __shared__ float red[2];
    if ((t & 63) == 0) red[t >> 6] = ss;
    __syncthreads();
    if (t == 0) c2[k] = red[0] + red[1];
}

// ---- main: 32 rows x 512 clusters per block, 256 threads = 4 waves (each 32x128) ----
__global__ __launch_bounds__(256, 3) void dec_soft_assign(
        const float* __restrict__ x, const unsigned short* __restrict__ cb,
        const float* __restrict__ c2g, float* __restrict__ out) {
    __shared__ __align__(16) unsigned short Alds[MT * APAD];   // 2.5 KB
    __shared__ __align__(16) unsigned short Blds[NCL * BK];    // 32 KB, [n][k-chunk] XOR-swizzled
    __shared__ float x2_lds[MT];
    __shared__ float rs_lds[MT][4];
    __shared__ float inv_lds[MT];

    const int t   = threadIdx.x;
    const int w   = t >> 6;        // wave 0..3
    const int l   = t & 63;
    const int q   = l >> 4;        // quad
    const int l15 = l & 15;
    const int m0  = blockIdx.x * MT;

    // A staging: thread t loads float4 of row ar, chunk ac4
    const int ar  = t >> 3;        // 0..31
    const int ac4 = t & 7;         // 0..7
    const float4* xp = (const float4*)(x + (m0 + ar) * DDIM) + ac4;

    // B staging: 512 rows x 4 chunks(16B) = 2048 chunks; chunk cl = i*256 + t.
    // Physical LDS slot (n, c') holds global k-chunk c = c' ^ ((n>>1)&3)  (bank swizzle).
    int bgo[8];
#pragma unroll
    for (int i = 0; i < 8; ++i) {
        int cl = i * 256 + t;
        int n  = cl >> 2;
        int cp = cl & 3;
        int cc = cp ^ ((n >> 1) & 3);
        bgo[i] = n * DDIM + cc * 8;          // short index (add kt*BK per step)
    }

    f32x4 acc[2][8];
#pragma unroll
    for (int mt = 0; mt < 2; ++mt)
#pragma unroll
        for (int nt = 0; nt < 8; ++nt)
            acc[mt][nt] = (f32x4){0.f, 0.f, 0.f, 0.f};

    float x2a = 0.f;
    float4 av = xp[0];

    for (int kt = 0; kt < 16; ++kt) {
        __syncthreads();                     // previous MFMA reads of LDS done
        // ---- stage A: fp32 -> bf16, accumulate ||x||^2 in fp32 ----
        x2a += av.x * av.x + av.y * av.y + av.z * av.z + av.w * av.w;
        short4_t a4;
        a4.x = (short)f2bf(av.x); a4.y = (short)f2bf(av.y);
        a4.z = (short)f2bf(av.z); a4.w = (short)f2bf(av.w);
        *(short4_t*)&Alds[ar * APAD + ac4 * 4] = a4;
        // ---- stage B: async 16B direct-to-LDS (lane-ordered dest, swizzled source) ----
#pragma unroll
        for (int i = 0; i < 8; ++i) {
            __builtin_amdgcn_global_load_lds(
                (const __attribute__((address_space(1))) void*)(cb + bgo[i] + kt * BK),
                (__attribute__((address_space(3))) void*)&Blds[(i * 256 + w * 64) * 8],
                16, 0, 0);
        }
        __syncthreads();                     // staging visible (vmcnt drained by barrier)
        if (kt < 15) av = xp[(kt + 1) * 8];  // prefetch next A over the MFMA phase

        // ---- MFMA phase: 2 (M) x 8 (N) tiles of 16x16, K=32 ----
        short8_t afr[2], bfr[8];
#pragma unroll
        for (int mt = 0; mt < 2; ++mt)
            afr[mt] = *(const short8_t*)&Alds[(mt * 16 + l15) * APAD + q * 8];
#pragma unroll
        for (int nt = 0; nt < 8; ++nt) {
            int n  = w * 128 + nt * 16 + l15;
            int pc = q ^ ((n >> 1) & 3);
            bfr[nt] = *(const short8_t*)&Blds[n * BK + pc * 8];
        }
#pragma unroll
        for (int nt = 0; nt < 8; ++nt) {
            acc[0][nt] = __builtin_amdgcn_mfma_f32_16x16x32_bf16(afr[0], bfr[nt], acc[0][nt], 0, 0, 0);
            acc[1][nt] = __builtin_amdgcn_mfma_f32_16x16x32_bf16(afr[1], bfr[nt], acc[1][nt], 0, 0, 0);
        }
    }

    // ---- x^2 per row: reduce the 8 staging lanes of each row ----
    x2a += __shfl_xor(x2a, 1, 64);
    x2a += __shfl_xor(x2a, 2, 64);
    x2a += __shfl_xor(x2a, 4, 64);
    if (ac4 == 0) x2_lds[ar] = x2a;
    __syncthreads();

    // ---- epilogue: dist2 -> clamp -> 1/(1+d), row sums ----
    float c2v[8];
#pragma unroll
    for (int nt = 0; nt < 8; ++nt)
        c2v[nt] = c2g[w * 128 + nt * 16 + l15];

    float rsum[2][4];
#pragma unroll
    for (int mt = 0; mt < 2; ++mt)
#pragma unroll
        for (int r = 0; r < 4; ++r) rsum[mt][r] = 0.f;

#pragma unroll
    for (int mt = 0; mt < 2; ++mt) {
#pragma unroll
        for (int r = 0; r < 4; ++r) {
            float xv = x2_lds[mt * 16 + q * 4 + r];
#pragma unroll
            for (int nt = 0; nt < 8; ++nt) {
                float d = xv + c2v[nt] - 2.0f * acc[mt][nt][r];
                d = fmaxf(d, 0.0f);
                float qq = __builtin_amdgcn_rcpf(1.0f + d);
                acc[mt][nt][r] = qq;         // reuse acc registers for q
                rsum[mt][r] += qq;
            }
        }
    }
    // reduce row partials across the 16 lanes sharing a row, then across 4 waves via LDS
#pragma unroll
    for (int mt = 0; mt < 2; ++mt)
#pragma unroll
        for (int r = 0; r < 4; ++r) {
            float s = rsum[mt][r];
            s += __shfl_xor(s, 1, 64);
            s += __shfl_xor(s, 2, 64);
            s += __shfl_xor(s, 4, 64);
            s += __shfl_xor(s, 8, 64);
            if (l15 == 0) rs_lds[mt * 16 + q * 4 + r][w] = s;
        }
    __syncthreads();
    if (t < MT) {
        float s = rs_lds[t][0] + rs_lds[t][1] + rs_lds[t][2] + rs_lds[t][3];
        inv_lds[t] = __builtin_amdgcn_rcpf(s);
    }
    __syncthreads();

    // ---- store normalized q (coalesced: 16 consecutive cols per quad) ----
#pragma unroll
    for (int mt = 0; mt < 2; ++mt)
#pragma unroll
        for (int r = 0; r < 4; ++r) {
            int row = mt * 16 + q * 4 + r;
            float inv = inv_lds[row];
            float* orow = out + (long)(m0 + row) * NCL + w * 128;
#pragma unroll
            for (int nt = 0; nt < 8; ++nt)
                orow[nt * 16 + l15] = acc[mt][nt][r] * inv;
        }
}

extern "C" void kernel_launch(void* const* d_in, const int* in_sizes, int n_in,
                              void* d_out, int out_size, void* d_ws, size_t ws_size,
                              hipStream_t stream) {
    const float* x       = (const float*)d_in[0];
    const float* centers = (const float*)d_in[1];
    float* out           = (float*)d_out;

    unsigned short* cb = (unsigned short*)d_ws;                         // 512*512 bf16 = 512 KB
    float* c2          = (float*)((char*)d_ws + NCL * DDIM * sizeof(unsigned short)); // 2 KB

    prep_centers<<<NCL, 128, 0, stream>>>(centers, cb, c2);
    dec_soft_assign<<<NROWS / MT, 256, 0, stream>>>(x, cb, c2, out);
}

// Round 2
// 504.037 us; speedup vs baseline: 1.1208x; 1.1208x over previous
//
#include <hip/hip_runtime.h>

// DEC soft assignment: q = rownorm(1/(1 + ||x-c||^2)), ALPHA=1 so power term is identity.
// bf16 MFMA for x.c^T (error budget: dq ~ 2e-7 << 4e-5 threshold); fp32 x^2/c^2/normalize.
// R2: MT 32->64 (halves per-CU B restream, 32 MFMA per barrier interval), wave tile 64x128.

typedef __attribute__((ext_vector_type(8))) short short8_t;
typedef __attribute__((ext_vector_type(4))) short short4_t;
typedef __attribute__((ext_vector_type(4))) float f32x4;

#define NROWS 131072
#define DDIM  512
#define NCL   512
#define BK    32
#define MT    64
#define APAD  36   // A row stride in shorts: 72B = 18 banks -> 16 distinct starts, 2-way-free b128

__device__ __forceinline__ unsigned short f2bf(float f) {
    unsigned u = __float_as_uint(f);
    u += 0x7FFFu + ((u >> 16) & 1u);
    return (unsigned short)(u >> 16);
}

// ---- prep: convert centers to bf16, compute ||c_k||^2 in fp32 ----
__global__ __launch_bounds__(128) void prep_centers(
        const float* __restrict__ c, unsigned short* __restrict__ cb,
        float* __restrict__ c2) {
    const int k = blockIdx.x, t = threadIdx.x;
    float4 v = ((const float4*)(c + k * DDIM))[t];
    float ss = v.x * v.x + v.y * v.y + v.z * v.z + v.w * v.w;
    short4_t s;
    s.x = (short)f2bf(v.x); s.y = (short)f2bf(v.y);
    s.z = (short)f2bf(v.z); s.w = (short)f2bf(v.w);
    ((short4_t*)(cb + k * DDIM))[t] = s;
#pragma unroll
    for (int off = 32; off >= 1; off >>= 1) ss += __shfl_xor(ss, off, 64);
    __shared__ float red[2];
    if ((t & 63) == 0) red[t >> 6] = ss;
    __syncthreads();
    if (t == 0) c2[k] = red[0] + red[1];
}

// ---- main: 64 rows x 512 clusters per block, 256 threads = 4 waves (each 64x128) ----
__global__ __launch_bounds__(256, 2) void dec_soft_assign(
        const float* __restrict__ x, const unsigned short* __restrict__ cb,
        const float* __restrict__ c2g, float* __restrict__ out) {
    __shared__ __align__(16) unsigned short Alds[MT * APAD];   // 4.5 KB
    __shared__ __align__(16) unsigned short Blds[NCL * BK];    // 32 KB, XOR-chunk swizzled
    __shared__ float x2_lds[MT];
    __shared__ float rs_lds[MT][4];
    __shared__ float inv_lds[MT];

    const int t   = threadIdx.x;
    const int w   = t >> 6;        // wave 0..3
    const int l   = t & 63;
    const int q   = l >> 4;        // quad
    const int l15 = l & 15;
    const int m0  = blockIdx.x * MT;

    // A staging: thread t owns row ar (one row), 8-elem k-chunk acj per step
    const int ar  = t >> 2;        // 0..63
    const int acj = t & 3;         // 0..3  (8 k-elems = 2 float4)
    const float4* xp = (const float4*)(x + (long)(m0 + ar) * DDIM) + acj * 2;

    // B staging: 512 cols x 4 chunks(16B) = 2048 chunks; chunk cl = i*256 + t.
    // Physical slot (n, cp) holds global k-chunk cc = cp ^ ((n>>1)&3)  (bank swizzle).
    int bgo[8];
#pragma unroll
    for (int i = 0; i < 8; ++i) {
        int cl = i * 256 + t;
        int n  = cl >> 2;
        int cp = cl & 3;
        int cc = cp ^ ((n >> 1) & 3);
        bgo[i] = n * DDIM + cc * 8;          // short index (add kt*BK per step)
    }

    f32x4 acc[4][8];
#pragma unroll
    for (int mt = 0; mt < 4; ++mt)
#pragma unroll
        for (int nt = 0; nt < 8; ++nt)
            acc[mt][nt] = (f32x4){0.f, 0.f, 0.f, 0.f};

    float x2a = 0.f;
    float4 av0 = xp[0], av1 = xp[1];

    for (int kt = 0; kt < 16; ++kt) {
        __syncthreads();                     // previous MFMA reads of LDS done
        // ---- stage A: fp32 -> bf16 (b128 write), accumulate ||x||^2 in fp32 ----
        x2a += av0.x * av0.x + av0.y * av0.y + av0.z * av0.z + av0.w * av0.w;
        x2a += av1.x * av1.x + av1.y * av1.y + av1.z * av1.z + av1.w * av1.w;
        short8_t a8;
        a8[0] = (short)f2bf(av0.x); a8[1] = (short)f2bf(av0.y);
        a8[2] = (short)f2bf(av0.z); a8[3] = (short)f2bf(av0.w);
        a8[4] = (short)f2bf(av1.x); a8[5] = (short)f2bf(av1.y);
        a8[6] = (short)f2bf(av1.z); a8[7] = (short)f2bf(av1.w);
        *(short8_t*)&Alds[ar * APAD + acj * 8] = a8;
        // ---- stage B: async 16B direct-to-LDS (lane-ordered dest, swizzled source) ----
#pragma unroll
        for (int i = 0; i < 8; ++i) {
            __builtin_amdgcn_global_load_lds(
                (const __attribute__((address_space(1))) void*)(cb + bgo[i] + kt * BK),
                (__attribute__((address_space(3))) void*)&Blds[(i * 256 + w * 64) * 8],
                16, 0, 0);
        }
        __syncthreads();                     // staging visible (vmcnt drained by barrier)
        if (kt < 15) { av0 = xp[(kt + 1) * 8]; av1 = xp[(kt + 1) * 8 + 1]; } // overlap MFMA

        // ---- MFMA phase: 4 (M) x 8 (N) tiles of 16x16, K=32 ----
        short8_t afr[4], bfr[8];
#pragma unroll
        for (int mt = 0; mt < 4; ++mt)
            afr[mt] = *(const short8_t*)&Alds[(mt * 16 + l15) * APAD + q * 8];
#pragma unroll
        for (int nt = 0; nt < 8; ++nt) {
            int n  = w * 128 + nt * 16 + l15;
            int pc = q ^ ((n >> 1) & 3);
            bfr[nt] = *(const short8_t*)&Blds[n * BK + pc * 8];
        }
#pragma unroll
        for (int nt = 0; nt < 8; ++nt)
#pragma unroll
            for (int mt = 0; mt < 4; ++mt)
                acc[mt][nt] = __builtin_amdgcn_mfma_f32_16x16x32_bf16(afr[mt], bfr[nt], acc[mt][nt], 0, 0, 0);
    }

    // ---- x^2 per row: reduce the 4 staging lanes of each row ----
    x2a += __shfl_xor(x2a, 1, 64);
    x2a += __shfl_xor(x2a, 2, 64);
    if (acj == 0) x2_lds[ar] = x2a;
    __syncthreads();

    // ---- epilogue: dist2 -> clamp -> 1/(1+d), row sums ----
    float c2v[8];
#pragma unroll
    for (int nt = 0; nt < 8; ++nt)
        c2v[nt] = c2g[w * 128 + nt * 16 + l15];

    float rsum[4][4];
#pragma unroll
    for (int mt = 0; mt < 4; ++mt)
#pragma unroll
        for (int r = 0; r < 4; ++r) rsum[mt][r] = 0.f;

#pragma unroll
    for (int mt = 0; mt < 4; ++mt) {
#pragma unroll
        for (int r = 0; r < 4; ++r) {
            float xv = x2_lds[mt * 16 + q * 4 + r];
#pragma unroll
            for (int nt = 0; nt < 8; ++nt) {
                float d = xv + c2v[nt] - 2.0f * acc[mt][nt][r];
                d = fmaxf(d, 0.0f);
                float qq = __builtin_amdgcn_rcpf(1.0f + d);
                acc[mt][nt][r] = qq;         // reuse acc registers for q
                rsum[mt][r] += qq;
            }
        }
    }
    // reduce row partials across 16 lanes sharing a row, then across 4 waves via LDS
#pragma unroll
    for (int mt = 0; mt < 4; ++mt)
#pragma unroll
        for (int r = 0; r < 4; ++r) {
            float s = rsum[mt][r];
            s += __shfl_xor(s, 1, 64);
            s += __shfl_xor(s, 2, 64);
            s += __shfl_xor(s, 4, 64);
            s += __shfl_xor(s, 8, 64);
            if (l15 == 0) rs_lds[mt * 16 + q * 4 + r][w] = s;
        }
    __syncthreads();
    if (t < MT) {
        float s = rs_lds[t][0] + rs_lds[t][1] + rs_lds[t][2] + rs_lds[t][3];
        inv_lds[t] = __builtin_amdgcn_rcpf(s);
    }
    __syncthreads();

    // ---- store normalized q (coalesced: 16 consecutive floats per quad) ----
#pragma unroll
    for (int mt = 0; mt < 4; ++mt)
#pragma unroll
        for (int r = 0; r < 4; ++r) {
            int row = mt * 16 + q * 4 + r;
            float inv = inv_lds[row];
            float* orow = out + (long)(m0 + row) * NCL + w * 128;
#pragma unroll
            for (int nt = 0; nt < 8; ++nt)
                orow[nt * 16 + l15] = acc[mt][nt][r] * inv;
        }
}

extern "C" void kernel_launch(void* const* d_in, const int* in_sizes, int n_in,
                              void* d_out, int out_size, void* d_ws, size_t ws_size,
                              hipStream_t stream) {
    const float* x       = (const float*)d_in[0];
    const float* centers = (const float*)d_in[1];
    float* out           = (float*)d_out;

    unsigned short* cb = (unsigned short*)d_ws;                         // 512*512 bf16 = 512 KB
    float* c2          = (float*)((char*)d_ws + NCL * DDIM * sizeof(unsigned short)); // 2 KB

    prep_centers<<<NCL, 128, 0, stream>>>(centers, cb, c2);
    dec_soft_assign<<<NROWS / MT, 256, 0, stream>>>(x, cb, c2, out);
}